// Round 14
// baseline (62.402 us; speedup 1.0000x reference)
//
#include <hip/hip_runtime.h>
#include <hip/hip_bf16.h>
#include <math.h>

#define F 64
#define TILE 16

typedef __attribute__((ext_vector_type(8))) short bf16x8;
typedef __attribute__((ext_vector_type(4))) float f32x4;

union BF8 { bf16x8 v; unsigned u[4]; };

#define LOG2E 1.4426950408889634f
#define INV_LOG2E 0.6931471805599453f

__device__ __forceinline__ float fast_exp(float x) {          // e^x
    return __builtin_amdgcn_exp2f(x * LOG2E);
}
__device__ __forceinline__ float fast_sigmoid(float x) {
    return __builtin_amdgcn_rcpf(1.0f + fast_exp(-x));
}
// silu(s) from precomputed exponentials: e^-s = ei*ej
//   silu(s) = s * rcp(1 + ei*ej)   -> 3 VALU + 1 trans (no exp2)
__device__ __forceinline__ float silu_pq(float i, float j, float ei, float ej) {
    return (i + j) * __builtin_amdgcn_rcpf(__builtin_fmaf(ei, ej, 1.0f));
}
// single-instruction pack: low16 = bf16(a), high16 = bf16(b)  (RNE)
__device__ __forceinline__ unsigned cvtpk(float a, float b) {
    unsigned r;
    asm("v_cvt_pk_bf16_f32 %0, %1, %2" : "=v"(r) : "v"(a), "v"(b));
    return r;
}
__device__ __forceinline__ short f2bf(float x) {
    __hip_bfloat16 h = __float2bfloat16(x);
    return __builtin_bit_cast(short, h);
}

// ---------------------------------------------------------------------------
// Kernel 1: per-node half layer-1 outputs (bias folded) AND their negated
// exponentials (layer-1 exp factorization: e^-(yi+yj) = ey_i * ey_j).
// ---------------------------------------------------------------------------
__global__ void precompute_yz(const float* __restrict__ x,
                              const float* __restrict__ lW1, const float* __restrict__ lb1,
                              const float* __restrict__ gW1, const float* __restrict__ gb1,
                              float* __restrict__ y, float* __restrict__ z,
                              float* __restrict__ ey, float* __restrict__ ez) {
    __shared__ float xs[F];
    const int i = blockIdx.x;
    const int f = threadIdx.x;
    xs[f] = x[i * F + f];
    __syncthreads();
    float accY = 0.f, accZ = 0.f;
#pragma unroll
    for (int k = 0; k < F; ++k) {
        const float xv = xs[k];
        accY += xv * lW1[k * F + f];
        accZ += xv * gW1[k * F + f];
    }
    const float yv = 0.5f * accY + 0.5f * lb1[f];
    const float zv = 0.5f * accZ + 0.5f * gb1[f];
    y[i * F + f] = yv;
    z[i * F + f] = zv;
    ey[i * F + f] = __builtin_amdgcn_exp2f(-LOG2E * yv);
    ez[i * F + f] = __builtin_amdgcn_exp2f(-LOG2E * zv);
}

// ---------------------------------------------------------------------------
// Kernel 2: pre-swizzle layer-2 weights into per-lane MFMA fragments
// (A-fragment of W^T == B-fragment of W, m89 layout), hi bf16 only,
// PRE-SCALED by LOG2E (layer-3 exp2 folding).
//   wf[ b*4096 + kt*2048 + ft*512 + lane*8 + e ]
//   = bf16(LOG2E * W_b[k][f]),  k = kt*32+(lane>>4)*8+e,  f = ft*16+(lane&15)
// ---------------------------------------------------------------------------
__global__ void prep_wfrags(const float* __restrict__ lW2,
                            const float* __restrict__ gW2,
                            short* __restrict__ wf) {
    const int idx = blockIdx.x * 256 + threadIdx.x;   // 0..8191
    const int e    = idx & 7;
    const int lane = (idx >> 3) & 63;
    const int ft   = (idx >> 9) & 3;
    const int kt   = (idx >> 11) & 1;
    const int b    = (idx >> 12) & 1;
    const int k = kt * 32 + ((lane >> 4) << 3) + e;
    const int f = ft * 16 + (lane & 15);
    const float* W = b ? gW2 : lW2;
    wf[idx] = f2bf(LOG2E * W[k * F + f]);
}

// ---------------------------------------------------------------------------
// One branch, ptb=2 blocked (two pairs' fragments live at a time): out2^T =
// W2'^T @ act1^T via MFMA (acc = LOG2E*out2), fused layer 3. W from GLOBAL
// (unchanged R11 path — isolates R12's failure to its LDS-W staging).
// ---------------------------------------------------------------------------
__device__ __forceinline__ void run_branch(
    const float (*si)[F + 4], const float (*sei)[F + 4],
    const float (*sj)[F + 4], const float (*sej)[F + 4],
    const short* __restrict__ wfb,       // branch base (4096 shorts, scaled)
    const float* sB2, const float* sW3,  // pre-scaled (LOG2E, 1/LOG2E)
    int w, int g, int c, float (&part)[4]) {

    const int l = g * 16 + c;

#pragma unroll
    for (int ptb = 0; ptb < 2; ++ptb) {
        // ---- B-fragments for pairs (4w + 2ptb + p, c), p=0,1 ----
        BF8 bf[2][2];
#pragma unroll
        for (int kt = 0; kt < 2; ++kt) {
            const float* pj  = &sj[c][kt * 32 + 8 * g];
            const float* pej = &sej[c][kt * 32 + 8 * g];
            const float4 j0v = *(const float4*)(pj);
            const float4 j1v = *(const float4*)(pj + 4);
            const float4 ej0 = *(const float4*)(pej);
            const float4 ej1 = *(const float4*)(pej + 4);
#pragma unroll
            for (int p = 0; p < 2; ++p) {
                const int row = 4 * w + 2 * ptb + p;               // wave-uniform
                const float* pi  = &si[row][kt * 32 + 8 * g];
                const float* pei = &sei[row][kt * 32 + 8 * g];
                const float4 i0v = *(const float4*)(pi);
                const float4 i1v = *(const float4*)(pi + 4);
                const float4 ei0 = *(const float4*)(pei);
                const float4 ei1 = *(const float4*)(pei + 4);
                bf[kt][p].u[0] = cvtpk(silu_pq(i0v.x, j0v.x, ei0.x, ej0.x),
                                       silu_pq(i0v.y, j0v.y, ei0.y, ej0.y));
                bf[kt][p].u[1] = cvtpk(silu_pq(i0v.z, j0v.z, ei0.z, ej0.z),
                                       silu_pq(i0v.w, j0v.w, ei0.w, ej0.w));
                bf[kt][p].u[2] = cvtpk(silu_pq(i1v.x, j1v.x, ei1.x, ej1.x),
                                       silu_pq(i1v.y, j1v.y, ei1.y, ej1.y));
                bf[kt][p].u[3] = cvtpk(silu_pq(i1v.z, j1v.z, ei1.z, ej1.z),
                                       silu_pq(i1v.w, j1v.w, ei1.w, ej1.w));
            }
        }

#pragma unroll
        for (int ft = 0; ft < 4; ++ft) {
            const short* base = wfb + ft * 512 + l * 8;
            const bf16x8 wh0 = *(const bf16x8*)(base);           // kt=0
            const bf16x8 wh1 = *(const bf16x8*)(base + 2048);    // kt=1
            const float4 b2v = *(const float4*)&sB2[ft * 16 + 4 * g];   // LOG2E*b2
            const float4 w3v = *(const float4*)&sW3[ft * 16 + 4 * g];   // w3/LOG2E
#pragma unroll
            for (int p = 0; p < 2; ++p) {
                f32x4 acc = (f32x4){b2v.x, b2v.y, b2v.z, b2v.w};  // scaled bias
                acc = __builtin_amdgcn_mfma_f32_16x16x32_bf16(wh0, bf[0][p].v, acc, 0, 0, 0);
                acc = __builtin_amdgcn_mfma_f32_16x16x32_bf16(wh1, bf[1][p].v, acc, 0, 0, 0);
                const float r0 = __builtin_amdgcn_rcpf(1.0f + __builtin_amdgcn_exp2f(-acc[0]));
                const float r1 = __builtin_amdgcn_rcpf(1.0f + __builtin_amdgcn_exp2f(-acc[1]));
                const float r2 = __builtin_amdgcn_rcpf(1.0f + __builtin_amdgcn_exp2f(-acc[2]));
                const float r3 = __builtin_amdgcn_rcpf(1.0f + __builtin_amdgcn_exp2f(-acc[3]));
                float pp = part[2 * ptb + p];
                pp = __builtin_fmaf(acc[0] * r0, w3v.x, pp);
                pp = __builtin_fmaf(acc[1] * r1, w3v.y, pp);
                pp = __builtin_fmaf(acc[2] * r2, w3v.z, pp);
                pp = __builtin_fmaf(acc[3] * r3, w3v.w, pp);
                part[2 * ptb + p] = pp;
            }
        }
    }
}

// ---------------------------------------------------------------------------
// Kernel 3: 16x16 pair tile per block (upper triangle), transposed MFMA.
// Uncapped; ptb=2 targets a natural VGPR <= 64 (occupancy step 72->64 is
// the last live lever; every forced cap spilled).
// ---------------------------------------------------------------------------
__global__ __launch_bounds__(256) void pair_mlp_mfma(
    const float* __restrict__ y, const float* __restrict__ z,
    const float* __restrict__ ey, const float* __restrict__ ez,
    const short* __restrict__ wf,
    const float* __restrict__ lb2, const float* __restrict__ lW3, const float* __restrict__ lb3,
    const float* __restrict__ gb2, const float* __restrict__ gW3, const float* __restrict__ gb3,
    float* __restrict__ out, int N) {

    __shared__ __align__(16) float smem[8960];   // 35840 B
    float (*ysi)[F + 4]  = (float (*)[F + 4])(smem + 0);      // 16x68 each
    float (*zsi)[F + 4]  = (float (*)[F + 4])(smem + 1088);
    float (*ysj)[F + 4]  = (float (*)[F + 4])(smem + 2176);
    float (*zsj)[F + 4]  = (float (*)[F + 4])(smem + 3264);
    float (*eysi)[F + 4] = (float (*)[F + 4])(smem + 4352);
    float (*ezsi)[F + 4] = (float (*)[F + 4])(smem + 5440);
    float (*eysj)[F + 4] = (float (*)[F + 4])(smem + 6528);
    float (*ezsj)[F + 4] = (float (*)[F + 4])(smem + 7616);
    float* sB2l = smem + 8704;
    float* sW3l = smem + 8768;
    float* sB2g = smem + 8832;
    float* sW3g = smem + 8896;
    // epilogue aliases (used only after a __syncthreads once y/z reads done)
    float (*valD)[TILE + 1] = (float (*)[TILE + 1])(smem + 0);
    float (*valT)[TILE + 1] = (float (*)[TILE + 1])(smem + 1088);

    const int bid = blockIdx.x;
    int tj = (int)((sqrtf(8.0f * (float)bid + 1.0f) - 1.0f) * 0.5f);
    while ((tj + 1) * (tj + 2) / 2 <= bid) ++tj;
    while (tj * (tj + 1) / 2 > bid) --tj;
    const int ti = bid - tj * (tj + 1) / 2;   // ti <= tj
    const int i0 = ti * TILE, j0 = tj * TILE;

    const int t = threadIdx.x;

    // ---- stage y/z/ey/ez row tiles ----
    {
        const int r = t >> 4;
        const int e4 = t & 15;
        const float4* yv  = (const float4*)y;
        const float4* zv  = (const float4*)z;
        const float4* eyv = (const float4*)ey;
        const float4* ezv = (const float4*)ez;
        const size_t ri = (size_t)(i0 + r) * (F / 4) + e4;
        const size_t rj = (size_t)(j0 + r) * (F / 4) + e4;
        *(float4*)&ysi[r][e4 * 4]  = yv[ri];
        *(float4*)&zsi[r][e4 * 4]  = zv[ri];
        *(float4*)&ysj[r][e4 * 4]  = yv[rj];
        *(float4*)&zsj[r][e4 * 4]  = zv[rj];
        *(float4*)&eysi[r][e4 * 4] = eyv[ri];
        *(float4*)&ezsi[r][e4 * 4] = ezv[ri];
        *(float4*)&eysj[r][e4 * 4] = eyv[rj];
        *(float4*)&ezsj[r][e4 * 4] = ezv[rj];
    }
    if (t < F) {
        sB2l[t] = lb2[t] * LOG2E;          // scaled into MFMA domain
        sW3l[t] = lW3[t] * INV_LOG2E;      // de-scaled at the dot product
        sB2g[t] = gb2[t] * LOG2E;
        sW3g[t] = gW3[t] * INV_LOG2E;
    }
    __syncthreads();

    const int w = t >> 6;     // wave 0..3
    const int l = t & 63;
    const int g = l >> 4;
    const int c = l & 15;

    float partL[4] = {0.f, 0.f, 0.f, 0.f};
    float partG[4] = {0.f, 0.f, 0.f, 0.f};
    run_branch(ysi, eysi, ysj, eysj, wf,        sB2l, sW3l, w, g, c, partL);
    run_branch(zsi, ezsi, zsj, ezsj, wf + 4096, sB2g, sW3g, w, g, c, partG);

    // ---- reduce across the 4 lane groups (features) ----
#pragma unroll
    for (int pt = 0; pt < 4; ++pt) {
        partL[pt] += __shfl_xor(partL[pt], 16, 64);
        partL[pt] += __shfl_xor(partL[pt], 32, 64);
        partG[pt] += __shfl_xor(partG[pt], 16, 64);
        partG[pt] += __shfl_xor(partG[pt], 32, 64);
    }

    const float b3l = lb3[0];
    const float b3g = gb3[0];

    __syncthreads();   // all y/z LDS reads complete before aliasing region

    if (g == 0) {
#pragma unroll
        for (int pt = 0; pt < 4; ++pt) {
            const float m3 = partL[pt] + b3l;
            const float g3 = partG[pt] + b3g;
            const float v = m3 * fast_sigmoid(g3);
            valD[4 * w + pt][c] = v;
            valT[c][4 * w + pt] = v;
        }
    }
    __syncthreads();

    // ---- single-phase coalesced stores of both mirrored tiles ----
    {
        const int r = t >> 4;
        const int cc = t & 15;
        out[(size_t)(i0 + r) * N + (j0 + cc)] = valD[r][cc];
        out[(size_t)(j0 + r) * N + (i0 + cc)] = valT[r][cc];
    }
}

extern "C" void kernel_launch(void* const* d_in, const int* in_sizes, int n_in,
                              void* d_out, int out_size, void* d_ws, size_t ws_size,
                              hipStream_t stream) {
    const float* node_feat = (const float*)d_in[0];
    const float* lW1 = (const float*)d_in[1];
    const float* lb1 = (const float*)d_in[2];
    const float* lW2 = (const float*)d_in[3];
    const float* lb2 = (const float*)d_in[4];
    const float* lW3 = (const float*)d_in[5];
    const float* lb3 = (const float*)d_in[6];
    const float* gW1 = (const float*)d_in[7];
    const float* gb1 = (const float*)d_in[8];
    const float* gW2 = (const float*)d_in[9];
    const float* gb2 = (const float*)d_in[10];
    const float* gW3 = (const float*)d_in[11];
    const float* gb3 = (const float*)d_in[12];

    const int N = in_sizes[0] / F;   // 1024

    float* y  = (float*)d_ws;                      // N*F floats
    float* z  = y  + (size_t)N * F;
    float* ey = z  + (size_t)N * F;
    float* ez = ey + (size_t)N * F;
    short* wfrag = (short*)(ez + (size_t)N * F);   // 8192 shorts (16 KB)

    precompute_yz<<<N, F, 0, stream>>>(node_feat, lW1, lb1, gW1, gb1, y, z, ey, ez);
    prep_wfrags<<<32, 256, 0, stream>>>(lW2, gW2, wfrag);

    const int nT = N / TILE;                   // 64
    const int nBlocks = nT * (nT + 1) / 2;     // 2080
    pair_mlp_mfma<<<nBlocks, 256, 0, stream>>>(y, z, ey, ez, wfrag,
                                               lb2, lW3, lb3,
                                               gb2, gW3, gb3,
                                               (float*)d_out, N);
}

// Round 15
// 44.594 us; speedup vs baseline: 1.3994x; 1.3994x over previous
//
#include <hip/hip_runtime.h>
#include <hip/hip_bf16.h>
#include <math.h>

#define F 64
#define TILE 16

typedef __attribute__((ext_vector_type(8))) short bf16x8;
typedef __attribute__((ext_vector_type(4))) float f32x4;

union BF8 { bf16x8 v; unsigned u[4]; };

#define LOG2E 1.4426950408889634f
#define INV_LOG2E 0.6931471805599453f

__device__ __forceinline__ float fast_exp(float x) {          // e^x
    return __builtin_amdgcn_exp2f(x * LOG2E);
}
__device__ __forceinline__ float fast_sigmoid(float x) {
    return __builtin_amdgcn_rcpf(1.0f + fast_exp(-x));
}
// silu(s) from precomputed exponentials: e^-s = ei*ej
//   silu(s) = s * rcp(1 + ei*ej)   -> 3 VALU + 1 trans (no exp2)
__device__ __forceinline__ float silu_pq(float i, float j, float ei, float ej) {
    return (i + j) * __builtin_amdgcn_rcpf(__builtin_fmaf(ei, ej, 1.0f));
}
// single-instruction pack: low16 = bf16(a), high16 = bf16(b)  (RNE)
__device__ __forceinline__ unsigned cvtpk(float a, float b) {
    unsigned r;
    asm("v_cvt_pk_bf16_f32 %0, %1, %2" : "=v"(r) : "v"(a), "v"(b));
    return r;
}
__device__ __forceinline__ short f2bf(float x) {
    __hip_bfloat16 h = __float2bfloat16(x);
    return __builtin_bit_cast(short, h);
}

// ---------------------------------------------------------------------------
// Kernel 1: per-node half layer-1 outputs (bias folded) AND their negated
// exponentials (layer-1 exp factorization: e^-(yi+yj) = ey_i * ey_j):
//   y[i][f] = 0.5*(x[i]@lW1)[f] + 0.5*lb1[f];  ey = exp(-y);  z/ez likewise.
// ---------------------------------------------------------------------------
__global__ void precompute_yz(const float* __restrict__ x,
                              const float* __restrict__ lW1, const float* __restrict__ lb1,
                              const float* __restrict__ gW1, const float* __restrict__ gb1,
                              float* __restrict__ y, float* __restrict__ z,
                              float* __restrict__ ey, float* __restrict__ ez) {
    __shared__ float xs[F];
    const int i = blockIdx.x;
    const int f = threadIdx.x;
    xs[f] = x[i * F + f];
    __syncthreads();
    float accY = 0.f, accZ = 0.f;
#pragma unroll
    for (int k = 0; k < F; ++k) {
        const float xv = xs[k];
        accY += xv * lW1[k * F + f];
        accZ += xv * gW1[k * F + f];
    }
    const float yv = 0.5f * accY + 0.5f * lb1[f];
    const float zv = 0.5f * accZ + 0.5f * gb1[f];
    y[i * F + f] = yv;
    z[i * F + f] = zv;
    ey[i * F + f] = __builtin_amdgcn_exp2f(-LOG2E * yv);
    ez[i * F + f] = __builtin_amdgcn_exp2f(-LOG2E * zv);
}

// ---------------------------------------------------------------------------
// Kernel 2: pre-swizzle layer-2 weights into per-lane MFMA fragments
// (A-fragment of W^T == B-fragment of W in the m89 layout), hi bf16 only,
// PRE-SCALED by LOG2E (layer-3 exp2 folding).
//   wf[ b*4096 + kt*2048 + ft*512 + lane*8 + e ]
//   = bf16(LOG2E * W_b[k][f]),  k = kt*32+(lane>>4)*8+e,  f = ft*16+(lane&15)
// ---------------------------------------------------------------------------
__global__ void prep_wfrags(const float* __restrict__ lW2,
                            const float* __restrict__ gW2,
                            short* __restrict__ wf) {
    const int idx = blockIdx.x * 256 + threadIdx.x;   // 0..8191
    const int e    = idx & 7;
    const int lane = (idx >> 3) & 63;
    const int ft   = (idx >> 9) & 3;
    const int kt   = (idx >> 11) & 1;
    const int b    = (idx >> 12) & 1;
    const int k = kt * 32 + ((lane >> 4) << 3) + e;
    const int f = ft * 16 + (lane & 15);
    const float* W = b ? gW2 : lW2;
    wf[idx] = f2bf(LOG2E * W[k * F + f]);
}

// ---------------------------------------------------------------------------
// One branch: out2^T = W2'^T @ act1^T via MFMA (acc = LOG2E*out2), fused
// layer 3: silu(out2)*w3 = acc*rcp(1+exp2(-acc)) * (w3/LOG2E).
// ---------------------------------------------------------------------------
__device__ __forceinline__ void run_branch(
    const float (*si)[F + 4], const float (*sei)[F + 4],
    const float (*sj)[F + 4], const float (*sej)[F + 4],
    const short* __restrict__ wfb,       // branch base (4096 shorts, scaled)
    const float* sB2, const float* sW3,  // pre-scaled (LOG2E, 1/LOG2E)
    int w, int g, int c, float (&part)[4]) {

    const int l = g * 16 + c;

    // ---- build act1^T B-fragments via factored exponentials ----
    BF8 bf[2][4];
#pragma unroll
    for (int kt = 0; kt < 2; ++kt) {
        const float* pj  = &sj[c][kt * 32 + 8 * g];
        const float* pej = &sej[c][kt * 32 + 8 * g];
        const float4 j0v = *(const float4*)(pj);
        const float4 j1v = *(const float4*)(pj + 4);
        const float4 ej0 = *(const float4*)(pej);
        const float4 ej1 = *(const float4*)(pej + 4);
#pragma unroll
        for (int pt = 0; pt < 4; ++pt) {
            const float* pi  = &si[4 * w + pt][kt * 32 + 8 * g];   // wave-uniform
            const float* pei = &sei[4 * w + pt][kt * 32 + 8 * g];
            const float4 i0v = *(const float4*)(pi);
            const float4 i1v = *(const float4*)(pi + 4);
            const float4 ei0 = *(const float4*)(pei);
            const float4 ei1 = *(const float4*)(pei + 4);
            bf[kt][pt].u[0] = cvtpk(silu_pq(i0v.x, j0v.x, ei0.x, ej0.x),
                                    silu_pq(i0v.y, j0v.y, ei0.y, ej0.y));
            bf[kt][pt].u[1] = cvtpk(silu_pq(i0v.z, j0v.z, ei0.z, ej0.z),
                                    silu_pq(i0v.w, j0v.w, ei0.w, ej0.w));
            bf[kt][pt].u[2] = cvtpk(silu_pq(i1v.x, j1v.x, ei1.x, ej1.x),
                                    silu_pq(i1v.y, j1v.y, ei1.y, ej1.y));
            bf[kt][pt].u[3] = cvtpk(silu_pq(i1v.z, j1v.z, ei1.z, ej1.z),
                                    silu_pq(i1v.w, j1v.w, ei1.w, ej1.w));
        }
    }

    part[0] = part[1] = part[2] = part[3] = 0.f;

#pragma unroll
    for (int ft = 0; ft < 4; ++ft) {
        const short* base = wfb + ft * 512 + l * 8;
        const bf16x8 wh0 = *(const bf16x8*)(base);           // kt=0
        const bf16x8 wh1 = *(const bf16x8*)(base + 2048);    // kt=1
        const float4 b2v = *(const float4*)&sB2[ft * 16 + 4 * g];   // LOG2E*b2
        const float4 w3v = *(const float4*)&sW3[ft * 16 + 4 * g];   // w3/LOG2E
#pragma unroll
        for (int pt = 0; pt < 4; ++pt) {
            f32x4 acc = (f32x4){b2v.x, b2v.y, b2v.z, b2v.w};  // scaled bias
            acc = __builtin_amdgcn_mfma_f32_16x16x32_bf16(wh0, bf[0][pt].v, acc, 0, 0, 0);
            acc = __builtin_amdgcn_mfma_f32_16x16x32_bf16(wh1, bf[1][pt].v, acc, 0, 0, 0);
            // silu(out2)*w3 with acc = LOG2E*out2 (exp2 neg-modifier is free)
            const float r0 = __builtin_amdgcn_rcpf(1.0f + __builtin_amdgcn_exp2f(-acc[0]));
            const float r1 = __builtin_amdgcn_rcpf(1.0f + __builtin_amdgcn_exp2f(-acc[1]));
            const float r2 = __builtin_amdgcn_rcpf(1.0f + __builtin_amdgcn_exp2f(-acc[2]));
            const float r3 = __builtin_amdgcn_rcpf(1.0f + __builtin_amdgcn_exp2f(-acc[3]));
            float p = part[pt];
            p = __builtin_fmaf(acc[0] * r0, w3v.x, p);
            p = __builtin_fmaf(acc[1] * r1, w3v.y, p);
            p = __builtin_fmaf(acc[2] * r2, w3v.z, p);
            p = __builtin_fmaf(acc[3] * r3, w3v.w, p);
            part[pt] = p;
        }
    }
}

// ---------------------------------------------------------------------------
// Kernel 3: 16x16 pair tile per block (upper triangle), transposed MFMA.
// Uncapped, natural VGPR 72 — the measured optimum. Occupancy lever closed
// by six experiments (R3/R4/R7/R10 cap-spills; R12 LDS-W corrupt; R14
// restructure VGPR-inflation).
// ---------------------------------------------------------------------------
__global__ __launch_bounds__(256) void pair_mlp_mfma(
    const float* __restrict__ y, const float* __restrict__ z,
    const float* __restrict__ ey, const float* __restrict__ ez,
    const short* __restrict__ wf,
    const float* __restrict__ lb2, const float* __restrict__ lW3, const float* __restrict__ lb3,
    const float* __restrict__ gb2, const float* __restrict__ gW3, const float* __restrict__ gb3,
    float* __restrict__ out, int N) {

    __shared__ __align__(16) float smem[8960];   // 35840 B
    float (*ysi)[F + 4]  = (float (*)[F + 4])(smem + 0);      // 16x68 each
    float (*zsi)[F + 4]  = (float (*)[F + 4])(smem + 1088);
    float (*ysj)[F + 4]  = (float (*)[F + 4])(smem + 2176);
    float (*zsj)[F + 4]  = (float (*)[F + 4])(smem + 3264);
    float (*eysi)[F + 4] = (float (*)[F + 4])(smem + 4352);
    float (*ezsi)[F + 4] = (float (*)[F + 4])(smem + 5440);
    float (*eysj)[F + 4] = (float (*)[F + 4])(smem + 6528);
    float (*ezsj)[F + 4] = (float (*)[F + 4])(smem + 7616);
    float* sB2l = smem + 8704;
    float* sW3l = smem + 8768;
    float* sB2g = smem + 8832;
    float* sW3g = smem + 8896;
    // epilogue aliases (used only after a __syncthreads once y/z reads done)
    float (*valD)[TILE + 1] = (float (*)[TILE + 1])(smem + 0);
    float (*valT)[TILE + 1] = (float (*)[TILE + 1])(smem + 1088);

    const int bid = blockIdx.x;
    int tj = (int)((sqrtf(8.0f * (float)bid + 1.0f) - 1.0f) * 0.5f);
    while ((tj + 1) * (tj + 2) / 2 <= bid) ++tj;
    while (tj * (tj + 1) / 2 > bid) --tj;
    const int ti = bid - tj * (tj + 1) / 2;   // ti <= tj
    const int i0 = ti * TILE, j0 = tj * TILE;

    const int t = threadIdx.x;

    // ---- stage y/z/ey/ez row tiles ----
    {
        const int r = t >> 4;
        const int e4 = t & 15;
        const float4* yv  = (const float4*)y;
        const float4* zv  = (const float4*)z;
        const float4* eyv = (const float4*)ey;
        const float4* ezv = (const float4*)ez;
        const size_t ri = (size_t)(i0 + r) * (F / 4) + e4;
        const size_t rj = (size_t)(j0 + r) * (F / 4) + e4;
        *(float4*)&ysi[r][e4 * 4]  = yv[ri];
        *(float4*)&zsi[r][e4 * 4]  = zv[ri];
        *(float4*)&ysj[r][e4 * 4]  = yv[rj];
        *(float4*)&zsj[r][e4 * 4]  = zv[rj];
        *(float4*)&eysi[r][e4 * 4] = eyv[ri];
        *(float4*)&ezsi[r][e4 * 4] = ezv[ri];
        *(float4*)&eysj[r][e4 * 4] = eyv[rj];
        *(float4*)&ezsj[r][e4 * 4] = ezv[rj];
    }
    if (t < F) {
        sB2l[t] = lb2[t] * LOG2E;          // scaled into MFMA domain
        sW3l[t] = lW3[t] * INV_LOG2E;      // de-scaled at the dot product
        sB2g[t] = gb2[t] * LOG2E;
        sW3g[t] = gW3[t] * INV_LOG2E;
    }
    __syncthreads();

    const int w = t >> 6;     // wave 0..3
    const int l = t & 63;
    const int g = l >> 4;
    const int c = l & 15;

    float partL[4], partG[4];
    run_branch(ysi, eysi, ysj, eysj, wf,        sB2l, sW3l, w, g, c, partL);
    run_branch(zsi, ezsi, zsj, ezsj, wf + 4096, sB2g, sW3g, w, g, c, partG);

    // ---- reduce across the 4 lane groups (features) ----
#pragma unroll
    for (int pt = 0; pt < 4; ++pt) {
        partL[pt] += __shfl_xor(partL[pt], 16, 64);
        partL[pt] += __shfl_xor(partL[pt], 32, 64);
        partG[pt] += __shfl_xor(partG[pt], 16, 64);
        partG[pt] += __shfl_xor(partG[pt], 32, 64);
    }

    const float b3l = lb3[0];
    const float b3g = gb3[0];

    __syncthreads();   // all y/z LDS reads complete before aliasing region

    if (g == 0) {
#pragma unroll
        for (int pt = 0; pt < 4; ++pt) {
            const float m3 = partL[pt] + b3l;
            const float g3 = partG[pt] + b3g;
            const float v = m3 * fast_sigmoid(g3);
            valD[4 * w + pt][c] = v;
            valT[c][4 * w + pt] = v;
        }
    }
    __syncthreads();

    // ---- single-phase coalesced stores of both mirrored tiles ----
    {
        const int r = t >> 4;
        const int cc = t & 15;
        out[(size_t)(i0 + r) * N + (j0 + cc)] = valD[r][cc];
        out[(size_t)(j0 + r) * N + (i0 + cc)] = valT[r][cc];
    }
}

extern "C" void kernel_launch(void* const* d_in, const int* in_sizes, int n_in,
                              void* d_out, int out_size, void* d_ws, size_t ws_size,
                              hipStream_t stream) {
    const float* node_feat = (const float*)d_in[0];
    const float* lW1 = (const float*)d_in[1];
    const float* lb1 = (const float*)d_in[2];
    const float* lW2 = (const float*)d_in[3];
    const float* lb2 = (const float*)d_in[4];
    const float* lW3 = (const float*)d_in[5];
    const float* lb3 = (const float*)d_in[6];
    const float* gW1 = (const float*)d_in[7];
    const float* gb1 = (const float*)d_in[8];
    const float* gW2 = (const float*)d_in[9];
    const float* gb2 = (const float*)d_in[10];
    const float* gW3 = (const float*)d_in[11];
    const float* gb3 = (const float*)d_in[12];

    const int N = in_sizes[0] / F;   // 1024

    float* y  = (float*)d_ws;                      // N*F floats
    float* z  = y  + (size_t)N * F;
    float* ey = z  + (size_t)N * F;
    float* ez = ey + (size_t)N * F;
    short* wfrag = (short*)(ez + (size_t)N * F);   // 8192 shorts (16 KB)

    precompute_yz<<<N, F, 0, stream>>>(node_feat, lW1, lb1, gW1, gb1, y, z, ey, ez);
    prep_wfrags<<<32, 256, 0, stream>>>(lW2, gW2, wfrag);

    const int nT = N / TILE;                   // 64
    const int nBlocks = nT * (nT + 1) / 2;     // 2080
    pair_mlp_mfma<<<nBlocks, 256, 0, stream>>>(y, z, ey, ez, wfrag,
                                               lb2, lW3, lb3,
                                               gb2, gW3, gb3,
                                               (float*)d_out, N);
}